// Round 1
// baseline (826.118 us; speedup 1.0000x reference)
//
#include <hip/hip_runtime.h>
#include <hip/hip_bf16.h>
#include <math.h>

#define E_DIM 512
#define H_DIM 1024
#define V_DIM 50257
#define NSTEPS 19
#define NB_LOGITS 1024   // blocks for logits kernel (4 waves each)
#define NB_GATES  256    // blocks for gates kernel

// ---------------- init: x = inp, h = c = 0 ----------------
__global__ void init_kernel(const float* __restrict__ inp,
                            float* __restrict__ x,
                            float* __restrict__ h,
                            float* __restrict__ c) {
    int i = threadIdx.x + blockIdx.x * blockDim.x;  // 1024 threads total
    if (i < E_DIM) x[i] = inp[i];
    if (i < H_DIM) { h[i] = 0.f; c[i] = 0.f; }
}

// ---------------- gates = W_ih @ x + b_ih + W_hh @ h + b_hh ----------------
// wave-per-row; x and h held in registers per lane; float4 coalesced weight reads
__global__ void gates_kernel(const float* __restrict__ Wih,
                             const float* __restrict__ Whh,
                             const float* __restrict__ bih,
                             const float* __restrict__ bhh,
                             const float* __restrict__ x,
                             const float* __restrict__ h,
                             float* __restrict__ gates) {
    const int lane = threadIdx.x & 63;
    const int wave = threadIdx.x >> 6;
    const int gw   = blockIdx.x * 4 + wave;
    const int NW   = gridDim.x * 4;

    const float4* x4 = (const float4*)x;   // 128 float4
    const float4* h4 = (const float4*)h;   // 256 float4
    float4 xr[2], hr[4];
#pragma unroll
    for (int j = 0; j < 2; ++j) xr[j] = x4[lane + j * 64];
#pragma unroll
    for (int j = 0; j < 4; ++j) hr[j] = h4[lane + j * 64];

    for (int row = gw; row < 4 * H_DIM; row += NW) {
        const float4* wi = (const float4*)(Wih + (size_t)row * E_DIM);
        const float4* wh = (const float4*)(Whh + (size_t)row * H_DIM);
        float s = 0.f;
#pragma unroll
        for (int j = 0; j < 2; ++j) {
            float4 w = wi[lane + j * 64];
            s += w.x * xr[j].x + w.y * xr[j].y + w.z * xr[j].z + w.w * xr[j].w;
        }
#pragma unroll
        for (int j = 0; j < 4; ++j) {
            float4 w = wh[lane + j * 64];
            s += w.x * hr[j].x + w.y * hr[j].y + w.z * hr[j].z + w.w * hr[j].w;
        }
#pragma unroll
        for (int off = 32; off; off >>= 1) s += __shfl_xor(s, off, 64);
        if (lane == 0) gates[row] = s + bih[row] + bhh[row];
    }
}

// ---------------- LSTM cell update ----------------
__global__ void cell_kernel(const float* __restrict__ gates,
                            float* __restrict__ c,
                            float* __restrict__ h) {
    int j = threadIdx.x;  // 1024 threads, 1 block
    if (j < H_DIM) {
        float iv = gates[j];
        float fv = gates[j + H_DIM];
        float gv = gates[j + 2 * H_DIM];
        float ov = gates[j + 3 * H_DIM];
        iv = 1.0f / (1.0f + expf(-iv));
        fv = 1.0f / (1.0f + expf(-fv));
        gv = tanhf(gv);
        ov = 1.0f / (1.0f + expf(-ov));
        float cv = fv * c[j] + iv * gv;
        c[j] = cv;
        h[j] = ov * tanhf(cv);
    }
}

// map float to order-preserving uint32
__device__ inline unsigned int fmap(float f) {
    unsigned int u = __float_as_uint(f);
    return (u & 0x80000000u) ? ~u : (u | 0x80000000u);
}

// ---------------- logits + per-block argmax partial ----------------
__global__ void logits_kernel(const float* __restrict__ Wlin,
                              const float* __restrict__ blin,
                              const float* __restrict__ h,
                              unsigned long long* __restrict__ partials) {
    const int lane = threadIdx.x & 63;
    const int wave = threadIdx.x >> 6;
    const int gw   = blockIdx.x * 4 + wave;
    const int NW   = gridDim.x * 4;

    const float4* h4 = (const float4*)h;
    float4 hr[4];
#pragma unroll
    for (int j = 0; j < 4; ++j) hr[j] = h4[lane + j * 64];

    float best = -INFINITY;
    int   bidx = 0x7fffffff;
    for (int row = gw; row < V_DIM; row += NW) {
        const float4* w4 = (const float4*)(Wlin + (size_t)row * H_DIM);
        float s = 0.f;
#pragma unroll
        for (int j = 0; j < 4; ++j) {
            float4 w = w4[lane + j * 64];
            s += w.x * hr[j].x + w.y * hr[j].y + w.z * hr[j].z + w.w * hr[j].w;
        }
#pragma unroll
        for (int off = 32; off; off >>= 1) s += __shfl_xor(s, off, 64);
        s += blin[row];  // all lanes hold full sum after butterfly
        if (s > best) { best = s; bidx = row; }  // rows increase -> first-max tie-break
    }

    __shared__ float bv[4];
    __shared__ int   bi[4];
    if (lane == 0) { bv[wave] = best; bi[wave] = bidx; }
    __syncthreads();
    if (threadIdx.x == 0) {
        float B = bv[0]; int I = bi[0];
        for (int w = 1; w < 4; ++w)
            if (bv[w] > B || (bv[w] == B && bi[w] < I)) { B = bv[w]; I = bi[w]; }
        unsigned long long p =
            ((unsigned long long)fmap(B) << 32) | (unsigned)(0xFFFFFFFFu - (unsigned)I);
        partials[blockIdx.x] = p;
    }
}

// ---------------- final argmax reduce + token write + embedding gather ----------------
__global__ void finalize_kernel(const unsigned long long* __restrict__ partials,
                                const float* __restrict__ emb,
                                float* __restrict__ x,
                                int* __restrict__ tok_out) {
    const int lane = threadIdx.x & 63;
    const int wave = threadIdx.x >> 6;
    unsigned long long best = 0;
    for (int i = threadIdx.x; i < NB_LOGITS; i += 256) {
        unsigned long long p = partials[i];
        if (p > best) best = p;
    }
#pragma unroll
    for (int off = 32; off; off >>= 1) {
        unsigned long long o = __shfl_xor(best, off, 64);
        if (o > best) best = o;
    }
    __shared__ unsigned long long sb[4];
    __shared__ int stok;
    if (lane == 0) sb[wave] = best;
    __syncthreads();
    if (threadIdx.x == 0) {
        unsigned long long B = sb[0];
        for (int w = 1; w < 4; ++w) if (sb[w] > B) B = sb[w];
        int tok = (int)(0xFFFFFFFFu - (unsigned)(B & 0xFFFFFFFFu));
        *tok_out = tok;
        stok = tok;
    }
    __syncthreads();
    int tok = stok;
    const float4* e4 = (const float4*)(emb + (size_t)tok * E_DIM);
    float4* x4 = (float4*)x;
    if (threadIdx.x < E_DIM / 4) x4[threadIdx.x] = e4[threadIdx.x];
}

extern "C" void kernel_launch(void* const* d_in, const int* in_sizes, int n_in,
                              void* d_out, int out_size, void* d_ws, size_t ws_size,
                              hipStream_t stream) {
    const float* inp  = (const float*)d_in[0];
    const float* Wih  = (const float*)d_in[1];
    const float* Whh  = (const float*)d_in[2];
    const float* bih  = (const float*)d_in[3];
    const float* bhh  = (const float*)d_in[4];
    const float* emb  = (const float*)d_in[5];
    const float* Wlin = (const float*)d_in[6];
    const float* blin = (const float*)d_in[7];
    int* toks = (int*)d_out;

    // workspace layout (bytes)
    char* ws = (char*)d_ws;
    float* x     = (float*)(ws + 0);        // 512 f
    float* h     = (float*)(ws + 2048);     // 1024 f
    float* c     = (float*)(ws + 6144);     // 1024 f
    float* gates = (float*)(ws + 10240);    // 4096 f
    unsigned long long* partials = (unsigned long long*)(ws + 26624);  // 1024 u64

    init_kernel<<<1, 1024, 0, stream>>>(inp, x, h, c);

    for (int step = 0; step < NSTEPS; ++step) {
        gates_kernel<<<NB_GATES, 256, 0, stream>>>(Wih, Whh, bih, bhh, x, h, gates);
        cell_kernel<<<1, 1024, 0, stream>>>(gates, c, h);
        logits_kernel<<<NB_LOGITS, 256, 0, stream>>>(Wlin, blin, h, partials);
        finalize_kernel<<<1, 256, 0, stream>>>(partials, emb, x, toks + step);
    }
}